// Round 8
// baseline (471.376 us; speedup 1.0000x reference)
//
#include <hip/hip_runtime.h>
#include <math.h>

#define TWO_PI 6.28318530717958647692f

typedef float f4 __attribute__((ext_vector_type(4)));

#define NBLK 256u

// Software grid barrier: device-scope arrival counter, agent-scope acquire
// spin, __threadfence() (agent fence -> cross-XCD L2 wb/inv) on both sides.
// Safe: 256 blocks <= 1 block/CU => unconditional co-residency.
__device__ __forceinline__ void gbar(unsigned* cnt, unsigned target) {
    __syncthreads();
    __threadfence();                       // release my block's writes
    if (threadIdx.x == 0) {
        atomicAdd(cnt, 1u);                // device scope by default
        while (__hip_atomic_load(cnt, __ATOMIC_ACQUIRE,
                                 __HIP_MEMORY_SCOPE_AGENT) < target)
            __builtin_amdgcn_s_sleep(4);
    }
    __syncthreads();
    __threadfence();                       // acquire: invalidate stale caches
}

// ---------------------------------------------------------------------------
// One kernel, 256 blocks x 256 threads, software grid barriers between the
// five phases (bodies identical to the proven r6 kernels, retiled for 256).
// ---------------------------------------------------------------------------
__global__ __launch_bounds__(256, 2) void mega(
        const float* __restrict__ x,
        const float* __restrict__ w_polar,
        const float* __restrict__ b_polar,
        const float* __restrict__ w_attn1,
        const float* __restrict__ b_attn1,
        const float* __restrict__ w_attn2,
        const float* __restrict__ b_attn2,
        float* __restrict__ pf,
        float* __restrict__ pp_t,
        float* __restrict__ q,
        float* __restrict__ att,
        float* __restrict__ out,
        unsigned* __restrict__ barcnt) {
    __shared__ __align__(16) float sp[16384];    // 64 KB, reused per phase
    int tid = threadIdx.x;
    int blk = blockIdx.x;

    // ---------------- P1: cartesian -> polar gather (524288 outputs) -------
    {
        float* w00s = sp;        float* w01s = sp + 128;
        float* w10s = sp + 256;  float* w11s = sp + 384;
        int*   o00s = (int*)(sp + 512);  int* o01s = (int*)(sp + 640);
        int*   o10s = (int*)(sp + 768);  int* o11s = (int*)(sp + 896);
        if (tid < 128) {
            int a = tid >> 3, r = tid & 7;
            float theta = (TWO_PI * (float)a) / 16.0f;
            float rad   = ((float)r + 0.5f) / 8.0f * 64.0f;
            float ys = 63.5f + rad * sinf(theta);
            float xs = 63.5f + rad * cosf(theta);
            float y0 = floorf(ys), x0 = floorf(xs);
            float wy = ys - y0,    wx = xs - x0;
            int y0i = min(max((int)y0, 0), 127);
            int y1i = min(max((int)y0 + 1, 0), 127);
            int x0i = min(max((int)x0, 0), 127);
            int x1i = min(max((int)x0 + 1, 0), 127);
            float valid = (ys >= 0.0f && ys <= 127.0f && xs >= 0.0f && xs <= 127.0f) ? 1.0f : 0.0f;
            w00s[tid] = valid * (1.0f - wy) * (1.0f - wx);
            w01s[tid] = valid * (1.0f - wy) * wx;
            w10s[tid] = valid * wy * (1.0f - wx);
            w11s[tid] = valid * wy * wx;
            o00s[tid] = y0i * 128 + x0i;
            o01s[tid] = y0i * 128 + x1i;
            o10s[tid] = y1i * 128 + x0i;
            o11s[tid] = y1i * 128 + x1i;
        }
        __syncthreads();
        int bin = tid & 127;                       // invariant across j
        float W0 = w00s[bin], W1 = w01s[bin], W2 = w10s[bin], W3 = w11s[bin];
        int O0 = o00s[bin], O1 = o01s[bin], O2 = o10s[bin], O3 = o11s[bin];
        #pragma unroll
        for (int j = 0; j < 8; ++j) {
            int t = blk * 2048 + j * 256 + tid;    // < 524288
            int img = t >> 7;
            const float* ib = x + ((size_t)img << 14);
            pf[t] = ib[O0] * W0 + ib[O1] * W1 + ib[O2] * W2 + ib[O3] * W3;
        }
    }
    gbar(barcnt, 1 * NBLK);

    // ---------------- P2: grouped 3x3 conv, pp_t[b][bin][oc], 2 roles ------
    {
        float* pfs = sp;            // 64*180 floats (halo stays zero)
        float* red = sp + 11520;    // 128*8
        for (int i = tid; i < 64 * 180; i += 256) pfs[i] = 0.0f;
        for (int rep = 0; rep < 2; ++rep) {
            int role = (blk << 1) | rep;           // < 512
            int b  = role >> 5;
            int g  = (role >> 3) & 3;
            int ot = role & 7;
            __syncthreads();                       // pfs/red safe to overwrite
            const float* src = pf + ((size_t)(b * 256 + g * 64) << 7);
            for (int i = tid; i < 8192; i += 256) {
                int ic = i >> 7, bin = i & 127;
                pfs[ic * 180 + ((bin >> 3) + 1) * 10 + (bin & 7) + 1] = src[i];
            }
            __syncthreads();
            int half = tid >> 7;
            int bt   = tid & 127;
            int a = bt >> 3, r = bt & 7;
            int oc0 = g * 64 + ot * 8;
            float acc[8];
            #pragma unroll
            for (int j = 0; j < 8; ++j) acc[j] = 0.0f;
            const float* wbase = w_polar + (size_t)oc0 * 576 + half * 288;
            const float* pbase = pfs + half * 32 * 180 + a * 10 + r;
            for (int ic = 0; ic < 32; ++ic) {
                float v[9];
                const float* base = pbase + ic * 180;
                #pragma unroll
                for (int dh = 0; dh < 3; ++dh)
                    #pragma unroll
                    for (int dw = 0; dw < 3; ++dw)
                        v[dh * 3 + dw] = base[dh * 10 + dw];
                #pragma unroll
                for (int j = 0; j < 8; ++j) {
                    const float* wp = wbase + j * 576 + ic * 9;
                    acc[j] += wp[0]*v[0] + wp[1]*v[1] + wp[2]*v[2]
                            + wp[3]*v[3] + wp[4]*v[4] + wp[5]*v[5]
                            + wp[6]*v[6] + wp[7]*v[7] + wp[8]*v[8];
                }
            }
            if (half) {
                #pragma unroll
                for (int j = 0; j < 8; ++j) red[bt * 8 + j] = acc[j];
            }
            __syncthreads();
            if (!half) {
                float* dst = pp_t + ((size_t)((b << 7) + bt)) * 256 + oc0;
                #pragma unroll
                for (int j = 0; j < 8; ++j)
                    dst[j] = acc[j] + red[bt * 8 + j] + b_polar[oc0 + j];
            }
        }
    }
    gbar(barcnt, 2 * NBLK);

    // ---------------- P3: q[b][bin][o] = W1 . pp_t row ---------------------
    {
        float* wl = sp;             // 16384 floats, XOR-swizzled [c][o]
        for (int i = tid; i < 16384; i += 256) {       // i = o*256 + c
            int o = i >> 8, c = i & 255;
            wl[(c << 6) + (o ^ (c & 31))] = w_attn1[i];
        }
        __syncthreads();
        #pragma unroll
        for (int rep = 0; rep < 2; ++rep) {
            int n = blk * 512 + rep * 256 + tid;   // covers 131072
            int b   = n >> 13;
            int bin = (n >> 6) & 127;
            int o   = n & 63;
            const float4* pr4 = (const float4*)(pp_t + ((size_t)((b << 7) + bin)) * 256);
            float acc = 0.0f;
            #pragma unroll 8
            for (int c4 = 0; c4 < 64; ++c4) {
                float4 p = pr4[c4];
                int c = c4 << 2;
                acc += wl[( c      << 6) + (o ^ ( c      & 31))] * p.x;
                acc += wl[((c + 1) << 6) + (o ^ ((c + 1) & 31))] * p.y;
                acc += wl[((c + 2) << 6) + (o ^ ((c + 2) & 31))] * p.z;
                acc += wl[((c + 3) << 6) + (o ^ ((c + 3) & 31))] * p.w;
            }
            q[n] = acc;
        }
    }
    gbar(barcnt, 3 * NBLK);

    // ---------------- P4: attention map (4 px/thread) ----------------------
    {
        float* qs  = sp;            // 8896 swizzled
        float* b1s = sp + 8896;
        float* w2s = sp + 8960;
        int b       = blk >> 4;                    // 16 blocks per batch
        int quarter = blk & 15;                    // 1024 px each
        const float* qb = q + ((size_t)b << 13);
        for (int i = tid; i < 8192; i += 256) {
            int bin = i >> 6, o = i & 63;
            qs[(bin >> 3) * 556 + (bin & 7) * 68 + o] = qb[i];
        }
        if (tid < 64) { b1s[tid] = b_attn1[tid]; w2s[tid] = w_attn2[tid]; }
        __syncthreads();
        float b2 = b_attn2[0];
        const float4* q4  = (const float4*)qs;
        const float4* b14 = (const float4*)b1s;
        const float4* w24 = (const float4*)w2s;
        #pragma unroll
        for (int k = 0; k < 4; ++k) {
            int p = (quarter << 10) + (k << 8) + tid;
            int h = p >> 7, w = p & 127;
            float dy = (float)h - 63.5f;
            float dx = (float)w - 63.5f;
            float rr = sqrtf(dy * dy + dx * dx);
            float th = atan2f(dy, dx);
            if (th < 0.0f) th += TWO_PI;
            float aa = th / TWO_PI * 16.0f;
            float a0 = floorf(aa);
            float wa = aa - a0;
            int ia0 = ((int)a0) & 15;
            int ia1 = (ia0 + 1) & 15;
            float ri = rr / 64.0f * 8.0f - 0.5f;
            float r0 = floorf(ri);
            float wr = ri - r0;
            int ir0 = (int)fminf(fmaxf(r0, 0.0f), 7.0f);
            int ir1 = (int)fminf(fmaxf(r0 + 1.0f, 0.0f), 7.0f);
            float valid = (rr <= 64.0f) ? 1.0f : 0.0f;
            float w00 = valid * (1.0f - wa) * (1.0f - wr);
            float w01 = valid * (1.0f - wa) * wr;
            float w10 = valid * wa * (1.0f - wr);
            float w11 = valid * wa * wr;
            int t00 = ia0 * 139 + ir0 * 17;
            int t01 = ia0 * 139 + ir1 * 17;
            int t10 = ia1 * 139 + ir0 * 17;
            int t11 = ia1 * 139 + ir1 * 17;
            float acc = b2;
            #pragma unroll
            for (int i = 0; i < 16; ++i) {
                float4 v00 = q4[t00 + i], v01 = q4[t01 + i];
                float4 v10 = q4[t10 + i], v11 = q4[t11 + i];
                float4 bb = b14[i], ww = w24[i];
                float sx = w00 * v00.x + w01 * v01.x + w10 * v10.x + w11 * v11.x;
                float sy = w00 * v00.y + w01 * v01.y + w10 * v10.y + w11 * v11.y;
                float sz = w00 * v00.z + w01 * v01.z + w10 * v10.z + w11 * v11.z;
                float sw = w00 * v00.w + w01 * v01.w + w10 * v10.w + w11 * v11.w;
                acc += fmaxf(sx + bb.x, 0.0f) * ww.x;
                acc += fmaxf(sy + bb.y, 0.0f) * ww.y;
                acc += fmaxf(sz + bb.z, 0.0f) * ww.z;
                acc += fmaxf(sw + bb.w, 0.0f) * ww.w;
            }
            att[((size_t)b << 14) + p] = 1.0f / (1.0f + __expf(-acc));
        }
    }
    gbar(barcnt, 4 * NBLK);

    // ---------------- P5: out = x * att (streaming, NT) --------------------
    {
        const f4* x4   = (const f4*)x;
        const f4* att4 = (const f4*)att;
        f4* out4 = (f4*)out;
        int idx = blk * 256 + tid;
        for (int i = idx; i < 16777216; i += 65536) {
            f4 xv = __builtin_nontemporal_load(&x4[i]);
            f4 av = att4[((i >> 20) << 12) | (i & 4095)];
            __builtin_nontemporal_store(xv * av, &out4[i]);
        }
    }
}

// ---------------------------------------------------------------------------
extern "C" void kernel_launch(void* const* d_in, const int* in_sizes, int n_in,
                              void* d_out, int out_size, void* d_ws, size_t ws_size,
                              hipStream_t stream) {
    const float* x       = (const float*)d_in[0];
    const float* w_polar = (const float*)d_in[1];
    const float* b_polar = (const float*)d_in[2];
    const float* w_attn1 = (const float*)d_in[3];
    const float* b_attn1 = (const float*)d_in[4];
    const float* w_attn2 = (const float*)d_in[5];
    const float* b_attn2 = (const float*)d_in[6];
    float* out = (float*)d_out;
    float* ws  = (float*)d_ws;

    float*    pf     = ws;                 // 524288 f  [b][c][a][r]
    float*    pp_t   = ws + 524288;        // 524288 f  [b][bin][c]
    float*    q      = ws + 1048576;       // 131072 f  [b][bin][o]
    float*    att    = ws + 1179648;       // 262144 f  [b][h][w]
    unsigned* barcnt = (unsigned*)(ws + 1572864);   // barrier counter

    hipMemsetAsync((void*)barcnt, 0, 64, stream);
    hipLaunchKernelGGL(mega, dim3(NBLK), dim3(256), 0, stream,
                       x, w_polar, b_polar, w_attn1, b_attn1, w_attn2, b_attn2,
                       pf, pp_t, q, att, out, barcnt);
}